// Round 1
// baseline (1787.385 us; speedup 1.0000x reference)
//
#include <hip/hip_runtime.h>

typedef __attribute__((ext_vector_type(4))) float f32x4;
typedef __attribute__((ext_vector_type(8))) short short8;
typedef __attribute__((ext_vector_type(8))) unsigned short ushort8;
typedef __attribute__((ext_vector_type(4))) unsigned short ushort4v;

#define DEV __device__ __forceinline__

constexpr int NTOK = 8192;       // B*L
constexpr int NCP  = 1152;       // padded proj out cols (1024 delta | 16 B | 16 C | 96 pad)
constexpr int MAXTILES = 68;
constexpr int NPAD = MAXTILES * 128;

DEV unsigned short f2bf(float f) {
  unsigned int u = __builtin_bit_cast(unsigned int, f);
  u += 0x7FFFu + ((u >> 16) & 1u);
  return (unsigned short)(u >> 16);
}
DEV float bf2f(unsigned short h) {
  unsigned int u = ((unsigned int)h) << 16;
  return __builtin_bit_cast(float, u);
}

// ---------------- conversions ----------------
__global__ __launch_bounds__(256) void conv_x_k(const float* __restrict__ x,
    unsigned short* __restrict__ xh, unsigned short* __restrict__ xl) {
  int i = (blockIdx.x * 256 + threadIdx.x) * 4;
  f32x4 v = *(const f32x4*)(x + i);
  ushort4v hv, lv;
#pragma unroll
  for (int j = 0; j < 4; ++j) {
    unsigned short hh = f2bf(v[j]);
    hv[j] = hh;
    lv[j] = f2bf(v[j] - bf2f(hh));
  }
  *(ushort4v*)(xh + i) = hv;
  *(ushort4v*)(xl + i) = lv;
}

__global__ __launch_bounds__(256) void conv_w_k(const float* __restrict__ Wd,
    const float* __restrict__ WB, const float* __restrict__ WC,
    unsigned short* __restrict__ wh, unsigned short* __restrict__ wl) {
  int o = blockIdx.x * 256 + threadIdx.x;   // NCP*1024 total, layout [n][k]
  int k = o & 1023, n = o >> 10;
  float v = 0.f;
  if (n < 1024) v = Wd[k * 1024 + n];
  else if (n < 1040) v = WB[k * 16 + (n - 1024)];
  else if (n < 1056) v = WC[k * 16 + (n - 1040)];
  unsigned short hh = f2bf(v);
  wh[o] = hh;
  wl[o] = f2bf(v - bf2f(hh));
}

__global__ __launch_bounds__(256) void conv_up_k(const float* __restrict__ w,
    unsigned short* __restrict__ o) {
  size_t i = (size_t)blockIdx.x * 256 + threadIdx.x;  // upT[e][f][d]
  int d = (int)(i & 1023);
  size_t rest = i >> 10;
  int f = (int)(rest & 4095);
  int e = (int)(rest >> 12);
  o[i] = f2bf(w[(((size_t)e * 1024 + d) * 4096) + f]);
}

__global__ __launch_bounds__(256) void conv_dn_k(const float* __restrict__ w,
    unsigned short* __restrict__ o) {
  size_t i = (size_t)blockIdx.x * 256 + threadIdx.x;  // dnT[e][d][f]
  int f = (int)(i & 4095);
  size_t rest = i >> 12;
  int d = (int)(rest & 1023);
  int e = (int)(rest >> 10);
  o[i] = f2bf(w[(((size_t)e * 4096 + f) * 1024) + d]);
}

// ---------------- GEMM (MODE 0: split proj, 1: up+silu, 2: down+scatter) ----------------
template<int MODE>
__global__ __launch_bounds__(256) void gemm_k(
    const unsigned short* __restrict__ A, const unsigned short* __restrict__ A2,
    const unsigned short* __restrict__ Bm, const unsigned short* __restrict__ B2,
    float* __restrict__ outF, unsigned short* __restrict__ outH,
    const float* __restrict__ bias,
    const int* __restrict__ perm, const float* __restrict__ t1w,
    const int* __restrict__ tile_e, const int* __restrict__ tile_r0,
    const int* __restrict__ tile_ve, const int* __restrict__ n_tiles)
{
  constexpr int K = (MODE == 2) ? 4096 : 1024;
  constexpr int KT = K / 64;
  constexpr bool SPLIT = (MODE == 0);
  __shared__ __align__(16) unsigned short lA[(SPLIT ? 2 : 1) * 128 * 64];
  __shared__ __align__(16) unsigned short lB[(SPLIT ? 2 : 1) * 128 * 64];

  const int t = threadIdx.x;
  const int bx = blockIdx.x;
  const int by = blockIdx.y;
  int e = 0, row0 = 0, vend = 0;
  if constexpr (MODE == 0) {
    row0 = by * 128;
  } else {
    if (by >= *n_tiles) return;
    e = tile_e[by]; row0 = tile_r0[by]; vend = tile_ve[by];
  }
  (void)vend;

  const int r8 = t >> 3;           // 0..31
  const int kc = (t & 7) * 8;      // k element offset
  const unsigned short* ap[4];
  const unsigned short* bp[4];
  ptrdiff_t da = 0, db = 0;
  if constexpr (SPLIT) { da = A2 - A; db = B2 - Bm; }
#pragma unroll
  for (int j = 0; j < 4; ++j) {
    int r = row0 + r8 + 32 * j;
    if constexpr (MODE == 1) {
      int tok = perm[r];
      ap[j] = A + (size_t)tok * 1024 + kc;
    } else if constexpr (MODE == 2) {
      ap[j] = A + (size_t)r * 4096 + kc;
    } else {
      ap[j] = A + (size_t)r * 1024 + kc;
    }
    int cb = bx * 128 + r8 + 32 * j;
    if constexpr (MODE == 0) bp[j] = Bm + (size_t)cb * 1024 + kc;
    else if constexpr (MODE == 1) bp[j] = Bm + ((size_t)e * 4096 + cb) * 1024 + kc;
    else bp[j] = Bm + ((size_t)e * 1024 + cb) * 4096 + kc;
  }

  const int w = t >> 6, lane = t & 63;
  const int wm = w >> 1, wn = w & 1;
  const int lr = lane & 15, lk = (lane >> 4) * 8;
  int aoffe[4], boffe[4];     // element offsets in LDS
#pragma unroll
  for (int i = 0; i < 4; ++i) {
    aoffe[i] = (wm * 64 + i * 16 + lr) * 64 + lk;
    boffe[i] = (wn * 64 + i * 16 + lr) * 64 + lk;
  }

  f32x4 acc[4][4];
#pragma unroll
  for (int i = 0; i < 4; ++i)
#pragma unroll
    for (int j = 0; j < 4; ++j) acc[i][j] = (f32x4)(0.f);

  ushort8 va[4], vb[4], va2[4], vb2[4];
#pragma unroll
  for (int j = 0; j < 4; ++j) {
    va[j] = *(const ushort8*)(ap[j]);
    vb[j] = *(const ushort8*)(bp[j]);
    if constexpr (SPLIT) {
      va2[j] = *(const ushort8*)(ap[j] + da);
      vb2[j] = *(const ushort8*)(bp[j] + db);
    }
    ap[j] += 64; bp[j] += 64;
  }

  for (int kt = 0; kt < KT; ++kt) {
    __syncthreads();
    {
      int so = t * 8;
#pragma unroll
      for (int j = 0; j < 4; ++j) {
        *(ushort8*)(lA + j * 2048 + so) = va[j];
        *(ushort8*)(lB + j * 2048 + so) = vb[j];
        if constexpr (SPLIT) {
          *(ushort8*)(lA + 8192 + j * 2048 + so) = va2[j];
          *(ushort8*)(lB + 8192 + j * 2048 + so) = vb2[j];
        }
      }
    }
    if (kt + 1 < KT) {
#pragma unroll
      for (int j = 0; j < 4; ++j) {
        va[j] = *(const ushort8*)(ap[j]);
        vb[j] = *(const ushort8*)(bp[j]);
        if constexpr (SPLIT) {
          va2[j] = *(const ushort8*)(ap[j] + da);
          vb2[j] = *(const ushort8*)(bp[j] + db);
        }
        ap[j] += 64; bp[j] += 64;
      }
    }
    __syncthreads();
#pragma unroll
    for (int kk = 0; kk < 2; ++kk) {
      short8 af[4], bfv[4], afl[4], bfl[4];
#pragma unroll
      for (int i = 0; i < 4; ++i) {
        af[i]  = *(const short8*)(lA + aoffe[i] + kk * 32);
        bfv[i] = *(const short8*)(lB + boffe[i] + kk * 32);
        if constexpr (SPLIT) {
          afl[i] = *(const short8*)(lA + 8192 + aoffe[i] + kk * 32);
          bfl[i] = *(const short8*)(lB + 8192 + boffe[i] + kk * 32);
        }
      }
#pragma unroll
      for (int mi = 0; mi < 4; ++mi)
#pragma unroll
        for (int ni = 0; ni < 4; ++ni) {
          acc[mi][ni] = __builtin_amdgcn_mfma_f32_16x16x32_bf16(af[mi], bfv[ni], acc[mi][ni], 0, 0, 0);
          if constexpr (SPLIT) {
            acc[mi][ni] = __builtin_amdgcn_mfma_f32_16x16x32_bf16(afl[mi], bfv[ni], acc[mi][ni], 0, 0, 0);
            acc[mi][ni] = __builtin_amdgcn_mfma_f32_16x16x32_bf16(af[mi], bfl[ni], acc[mi][ni], 0, 0, 0);
          }
        }
    }
  }

  // epilogue: C/D layout col=lane&15, row=(lane>>4)*4+q  [m89-verified]
#pragma unroll
  for (int mi = 0; mi < 4; ++mi) {
#pragma unroll
    for (int ni = 0; ni < 4; ++ni) {
      int col = bx * 128 + wn * 64 + ni * 16 + lr;
#pragma unroll
      for (int q = 0; q < 4; ++q) {
        int rl = wm * 64 + mi * 16 + (lane >> 4) * 4 + q;
        float v = acc[mi][ni][q];
        if constexpr (MODE == 0) {
          outF[(size_t)(row0 + rl) * NCP + col] = v;
        } else if constexpr (MODE == 1) {
          float z = v + bias[e * 4096 + col];
          float sg = 1.f / (1.f + __expf(-z));
          outH[(size_t)(row0 + rl) * 4096 + col] = f2bf(z * sg);
        } else {
          int pos = row0 + rl;
          if (pos < vend) {
            int tok = perm[pos];
            float val = (v + bias[e * 1024 + col]) * t1w[tok];
            outF[(size_t)tok * 1024 + col] = val;
          }
        }
      }
    }
  }
}

// ---------------- selective scan ----------------
constexpr int PF = 16;
__global__ __launch_bounds__(256) void scan_k(
    const float* __restrict__ P, const float* __restrict__ x,
    const float* __restrict__ A_log, const float* __restrict__ D_param,
    const float* __restrict__ bd, const float* __restrict__ bB, const float* __restrict__ bC,
    float* __restrict__ ssm, unsigned short* __restrict__ ssmbf)
{
  const int t = threadIdx.x;
  const int s = t & 15, dl = t >> 4;
  const int b = blockIdx.x >> 6;
  const int d = (blockIdx.x & 63) * 16 + dl;
  const float Ads = -__expf(A_log[d * 16 + s]);
  const float bBs = bB[s], bCs = bC[s], bdd = bd[d], Dp = D_param[d];
  const float* Pb = P + (size_t)b * 2048 * NCP;
  const float* xb = x + (size_t)b * 2048 * 1024;

  float z[PF], xr[PF], brr[PF], cr[PF];
#pragma unroll
  for (int j = 0; j < PF; ++j) {
    int base = j * NCP;
    z[j] = Pb[base + d]; brr[j] = Pb[base + 1024 + s]; cr[j] = Pb[base + 1040 + s];
    xr[j] = xb[j * 1024 + d];
  }
  float h = 0.f;
  size_t obase = ((size_t)b * 2048) * 1024 + d;
  constexpr int NB = 2048 / PF;
  for (int lb = 0; lb < NB; ++lb) {
    float z2[PF], x2[PF], b2[PF], c2[PF];
    if (lb + 1 < NB) {
      const float* Pn = Pb + (size_t)(lb + 1) * PF * NCP;
      const float* xn = xb + (size_t)(lb + 1) * PF * 1024;
#pragma unroll
      for (int j = 0; j < PF; ++j) {
        z2[j] = Pn[j * NCP + d]; b2[j] = Pn[j * NCP + 1024 + s]; c2[j] = Pn[j * NCP + 1040 + s];
        x2[j] = xn[j * 1024 + d];
      }
    }
#pragma unroll
    for (int j = 0; j < PF; ++j) {
      float zz = z[j] + bdd;
      float delta = fmaxf(zz, 0.f) + log1pf(__expf(-fabsf(zz)));   // stable softplus
      float dA = delta * Ads;
      float barA = __expf(fminf(dA, 2.f));
      float Bv = brr[j] + bBs;
      float Cv = cr[j] + bCs;
      float barB = fminf(fmaxf(delta * Bv, -2.f), 2.f);
      h = fminf(fmaxf(barA * h + barB * xr[j], -100.f), 100.f);
      float y = h * Cv;
      y += __shfl_xor(y, 1); y += __shfl_xor(y, 2);
      y += __shfl_xor(y, 4); y += __shfl_xor(y, 8);
      if (s == 0) {
        float val = y + xr[j] * Dp;
        size_t o = obase + (size_t)(lb * PF + j) * 1024;
        ssm[o] = val;
        ssmbf[o] = f2bf(val);
      }
    }
    if (lb + 1 < NB) {
#pragma unroll
      for (int j = 0; j < PF; ++j) { z[j] = z2[j]; xr[j] = x2[j]; brr[j] = b2[j]; cr[j] = c2[j]; }
    }
  }
}

// ---------------- routing ----------------
__global__ __launch_bounds__(256) void route_k(
    const float* __restrict__ ssm, const float* __restrict__ Wr, const float* __restrict__ br,
    float* __restrict__ t1w, int* __restrict__ t1i, int* __restrict__ counts)
{
  int w = threadIdx.x >> 6, lane = threadIdx.x & 63;
  int n = blockIdx.x * 4 + w;
  const float* row = ssm + (size_t)n * 1024;
  float a0 = 0, a1 = 0, a2 = 0, a3 = 0;
  for (int i = lane; i < 1024; i += 64) {
    float v = row[i];
    f32x4 wr = *(const f32x4*)(Wr + i * 4);
    a0 += v * wr[0]; a1 += v * wr[1]; a2 += v * wr[2]; a3 += v * wr[3];
  }
#pragma unroll
  for (int off = 32; off; off >>= 1) {
    a0 += __shfl_xor(a0, off); a1 += __shfl_xor(a1, off);
    a2 += __shfl_xor(a2, off); a3 += __shfl_xor(a3, off);
  }
  a0 += br[0]; a1 += br[1]; a2 += br[2]; a3 += br[3];
  float m = a0; int idx = 0;
  if (a1 > m) { m = a1; idx = 1; }
  if (a2 > m) { m = a2; idx = 2; }
  if (a3 > m) { m = a3; idx = 3; }
  float denom = __expf(a0 - m) + __expf(a1 - m) + __expf(a2 - m) + __expf(a3 - m);
  if (lane == 0) {
    t1w[n] = 1.f / denom;
    t1i[n] = idx;
    atomicAdd(&counts[idx], 1);
  }
}

// misc layout (ints): counts@0 cursors@4 base@8 ntiles@12 tile_e@16 tile_r0@96 tile_ve@176
__global__ void build_k(int* misc, int* perm)
{
  if (threadIdx.x != 0 || blockIdx.x != 0) return;
  int* counts = misc; int* cursors = misc + 4; int* base = misc + 8;
  int* ntiles = misc + 12; int* te = misc + 16; int* tr = misc + 96; int* tv = misc + 176;
  int bpos = 0, tt = 0;
  for (int e = 0; e < 4; ++e) {
    base[e] = bpos; cursors[e] = 0;
    int c = counts[e];
    int nt = (c + 127) >> 7;
    for (int i = 0; i < nt; ++i) { te[tt] = e; tr[tt] = bpos + i * 128; tv[tt] = bpos + c; ++tt; }
    for (int p = bpos + c; p < bpos + nt * 128; ++p) perm[p] = 0;
    bpos += nt * 128;
  }
  *ntiles = tt;
}

__global__ __launch_bounds__(256) void scatter_k(const int* __restrict__ t1i,
    int* misc, int* __restrict__ perm)
{
  int n = blockIdx.x * 256 + threadIdx.x;
  int e = t1i[n];
  int pos = atomicAdd(&misc[4 + e], 1);
  perm[misc[8 + e] + pos] = n;
}

// ---------------- add + layernorm (in place on d_out) ----------------
__global__ __launch_bounds__(256) void ln_k(
    float* __restrict__ out, const float* __restrict__ ssm,
    const float* __restrict__ lnw, const float* __restrict__ lnb)
{
  __shared__ float red[8];
  int n = blockIdx.x, t = threadIdx.x;
  size_t base = (size_t)n * 1024 + t * 4;
  f32x4 a = *(const f32x4*)(out + base);
  f32x4 bsm = *(const f32x4*)(ssm + base);
  float o[4]; float sum = 0, sq = 0;
#pragma unroll
  for (int j = 0; j < 4; ++j) { o[j] = a[j] + bsm[j]; sum += o[j]; sq += o[j] * o[j]; }
#pragma unroll
  for (int off = 32; off; off >>= 1) { sum += __shfl_xor(sum, off); sq += __shfl_xor(sq, off); }
  int w = t >> 6;
  if ((t & 63) == 0) { red[w] = sum; red[4 + w] = sq; }
  __syncthreads();
  sum = red[0] + red[1] + red[2] + red[3];
  sq  = red[4] + red[5] + red[6] + red[7];
  float mu = sum * (1.f / 1024.f);
  float var = sq * (1.f / 1024.f) - mu * mu;
  float rs = rsqrtf(var + 1e-5f);
  f32x4 r;
#pragma unroll
  for (int j = 0; j < 4; ++j) {
    int c = t * 4 + j;
    r[j] = (o[j] - mu) * rs * lnw[c] + lnb[c];
  }
  *(f32x4*)(out + base) = r;
}

// ---------------- launch ----------------
extern "C" void kernel_launch(void* const* d_in, const int* in_sizes, int n_in,
                              void* d_out, int out_size, void* d_ws, size_t ws_size,
                              hipStream_t stream)
{
  (void)in_sizes; (void)n_in; (void)out_size;
  const float* x       = (const float*)d_in[0];
  const float* A_log   = (const float*)d_in[1];
  const float* D_param = (const float*)d_in[2];
  const float* Wd      = (const float*)d_in[3];
  const float* bd      = (const float*)d_in[4];
  const float* WB      = (const float*)d_in[5];
  const float* bB      = (const float*)d_in[6];
  const float* WC      = (const float*)d_in[7];
  const float* bC      = (const float*)d_in[8];
  const float* Wr      = (const float*)d_in[9];
  const float* br      = (const float*)d_in[10];
  const float* up_w    = (const float*)d_in[11];
  const float* up_b    = (const float*)d_in[12];
  const float* down_w  = (const float*)d_in[13];
  const float* down_b  = (const float*)d_in[14];
  const float* ln_w    = (const float*)d_in[15];
  const float* ln_b    = (const float*)d_in[16];
  float* out = (float*)d_out;

  char* ws = (char*)d_ws;
  size_t off = 0;
  auto alloc = [&](size_t bytes) { size_t o = off; off += (bytes + 255) & ~(size_t)255; return o; };
  size_t oXh  = alloc((size_t)NTOK * 1024 * 2);
  size_t oXl  = alloc((size_t)NTOK * 1024 * 2);
  size_t oWh  = alloc((size_t)NCP * 1024 * 2);
  size_t oWl  = alloc((size_t)NCP * 1024 * 2);
  size_t oP   = alloc((size_t)NTOK * NCP * 4);
  size_t oSSM = alloc((size_t)NTOK * 1024 * 4);
  size_t oSBF = alloc((size_t)NTOK * 1024 * 2);
  size_t oUp  = alloc((size_t)4 * 4096 * 1024 * 2);
  size_t oDn  = alloc((size_t)4 * 4096 * 1024 * 2);
  size_t oHid = alloc((size_t)NPAD * 4096 * 2);
  size_t oT1w = alloc((size_t)NTOK * 4);
  size_t oT1i = alloc((size_t)NTOK * 4);
  size_t oPerm= alloc((size_t)NPAD * 4);
  size_t oMisc= alloc(1024);
  if (ws_size < off) return;   // distinctive failure: absmax == stub's 8.5

  unsigned short* Xh  = (unsigned short*)(ws + oXh);
  unsigned short* Xl  = (unsigned short*)(ws + oXl);
  unsigned short* Wh  = (unsigned short*)(ws + oWh);
  unsigned short* Wl  = (unsigned short*)(ws + oWl);
  float*          Pf  = (float*)(ws + oP);
  float*          SSM = (float*)(ws + oSSM);
  unsigned short* SBF = (unsigned short*)(ws + oSBF);
  unsigned short* UpT = (unsigned short*)(ws + oUp);
  unsigned short* DnT = (unsigned short*)(ws + oDn);
  unsigned short* Hid = (unsigned short*)(ws + oHid);
  float*          T1w = (float*)(ws + oT1w);
  int*            T1i = (int*)(ws + oT1i);
  int*            perm= (int*)(ws + oPerm);
  int*            misc= (int*)(ws + oMisc);

  hipMemsetAsync(misc, 0, 16, stream);                         // counts = 0
  conv_x_k <<<8192, 256, 0, stream>>>(x, Xh, Xl);
  conv_w_k <<<4608, 256, 0, stream>>>(Wd, WB, WC, Wh, Wl);
  conv_up_k<<<65536, 256, 0, stream>>>(up_w, UpT);
  conv_dn_k<<<65536, 256, 0, stream>>>(down_w, DnT);

  gemm_k<0><<<dim3(9, 64), 256, 0, stream>>>(Xh, Xl, Wh, Wl, Pf, nullptr, nullptr,
      nullptr, nullptr, nullptr, nullptr, nullptr, nullptr);

  scan_k<<<256, 256, 0, stream>>>(Pf, x, A_log, D_param, bd, bB, bC, SSM, SBF);

  route_k<<<2048, 256, 0, stream>>>(SSM, Wr, br, T1w, T1i, misc);
  build_k<<<1, 1, 0, stream>>>(misc, perm);
  scatter_k<<<32, 256, 0, stream>>>(T1i, misc, perm);

  gemm_k<1><<<dim3(32, MAXTILES), 256, 0, stream>>>(SBF, nullptr, UpT, nullptr,
      nullptr, Hid, up_b, perm, nullptr, misc + 16, misc + 96, misc + 176, misc + 12);
  gemm_k<2><<<dim3(8, MAXTILES), 256, 0, stream>>>(Hid, nullptr, DnT, nullptr,
      out, nullptr, down_b, perm, T1w, misc + 16, misc + 96, misc + 176, misc + 12);

  ln_k<<<8192, 256, 0, stream>>>(out, SSM, ln_w, ln_b);
}

// Round 3
// 917.134 us; speedup vs baseline: 1.9489x; 1.9489x over previous
//
#include <hip/hip_runtime.h>

typedef __attribute__((ext_vector_type(4))) float f32x4;
typedef __attribute__((ext_vector_type(8))) short short8;
typedef __attribute__((ext_vector_type(8))) unsigned short ushort8;
typedef __attribute__((ext_vector_type(4))) unsigned short ushort4v;

#define DEV __device__ __forceinline__

constexpr int NTOK = 8192;       // B*L
constexpr int NCP  = 1152;       // padded proj out cols (1024 delta | 16 B | 16 C | 96 pad)
constexpr int MAXTILES = 68;
constexpr int NPAD = MAXTILES * 128;
constexpr int NCHUNK = 16;
constexpr int CLEN = 2048 / NCHUNK;   // 128

DEV unsigned short f2bf(float f) {
  unsigned int u = __builtin_bit_cast(unsigned int, f);
  u += 0x7FFFu + ((u >> 16) & 1u);
  return (unsigned short)(u >> 16);
}
DEV float bf2f(unsigned short h) {
  unsigned int u = ((unsigned int)h) << 16;
  return __builtin_bit_cast(float, u);
}

// ---------------- conversions ----------------
__global__ __launch_bounds__(256) void conv_x_k(const float* __restrict__ x,
    unsigned short* __restrict__ xh, unsigned short* __restrict__ xl) {
  int i = (blockIdx.x * 256 + threadIdx.x) * 4;
  f32x4 v = *(const f32x4*)(x + i);
  ushort4v hv, lv;
#pragma unroll
  for (int j = 0; j < 4; ++j) {
    unsigned short hh = f2bf(v[j]);
    hv[j] = hh;
    lv[j] = f2bf(v[j] - bf2f(hh));
  }
  *(ushort4v*)(xh + i) = hv;
  *(ushort4v*)(xl + i) = lv;
}

__global__ __launch_bounds__(256) void conv_w_k(const float* __restrict__ Wd,
    const float* __restrict__ WB, const float* __restrict__ WC,
    unsigned short* __restrict__ wh, unsigned short* __restrict__ wl) {
  int o = blockIdx.x * 256 + threadIdx.x;   // NCP*1024 total, layout [n][k]
  int k = o & 1023, n = o >> 10;
  float v = 0.f;
  if (n < 1024) v = Wd[k * 1024 + n];
  else if (n < 1040) v = WB[k * 16 + (n - 1024)];
  else if (n < 1056) v = WC[k * 16 + (n - 1040)];
  unsigned short hh = f2bf(v);
  wh[o] = hh;
  wl[o] = f2bf(v - bf2f(hh));
}

// LDS-tiled transpose + f32->bf16: in [E][R][C] -> out [E][C][R]
__global__ __launch_bounds__(256) void trans_k(const float* __restrict__ in,
    unsigned short* __restrict__ out, int R, int C) {
  __shared__ float tile[32][33];
  int e = blockIdx.z;
  int r0 = blockIdx.y * 32, c0 = blockIdx.x * 32;
  int r = threadIdx.x >> 5, cc = threadIdx.x & 31;
  const float* src = in + ((size_t)e * R + r0) * C + c0;
#pragma unroll
  for (int j = 0; j < 4; ++j) tile[r + j * 8][cc] = src[(size_t)(r + j * 8) * C + cc];
  __syncthreads();
  unsigned short* dst = out + ((size_t)e * C + c0) * R + r0;
#pragma unroll
  for (int j = 0; j < 4; ++j) dst[(size_t)(r + j * 8) * R + cc] = f2bf(tile[cc][r + j * 8]);
}

// ---------------- GEMM (MODE 0: split proj, 1: up+silu, 2: down+scatter) ----------------
template<int MODE>
__global__ __launch_bounds__(256) void gemm_k(
    const unsigned short* __restrict__ A, const unsigned short* __restrict__ A2,
    const unsigned short* __restrict__ Bm, const unsigned short* __restrict__ B2,
    float* __restrict__ outF, unsigned short* __restrict__ outH,
    const float* __restrict__ bias, const float* __restrict__ b1, const float* __restrict__ b2,
    const int* __restrict__ perm, const float* __restrict__ t1w,
    const int* __restrict__ tile_e, const int* __restrict__ tile_r0,
    const int* __restrict__ tile_ve, const int* __restrict__ n_tiles)
{
  constexpr int K = (MODE == 2) ? 4096 : 1024;
  constexpr int KT = K / 64;
  constexpr bool SPLIT = (MODE == 0);
  __shared__ __align__(16) unsigned short lA[(SPLIT ? 2 : 1) * 128 * 64];
  __shared__ __align__(16) unsigned short lB[(SPLIT ? 2 : 1) * 128 * 64];

  const int t = threadIdx.x;
  const int bx = blockIdx.x;
  const int by = blockIdx.y;
  int e = 0, row0 = 0, vend = 0;
  if constexpr (MODE == 0) {
    row0 = by * 128;
  } else {
    if (by >= *n_tiles) return;
    e = tile_e[by]; row0 = tile_r0[by]; vend = tile_ve[by];
  }
  (void)vend;

  const int r8 = t >> 3;           // 0..31
  const int kc = (t & 7) * 8;      // k element offset
  const unsigned short* ap[4];
  const unsigned short* bp[4];
  ptrdiff_t da = 0, db = 0;
  if constexpr (SPLIT) { da = A2 - A; db = B2 - Bm; }
#pragma unroll
  for (int j = 0; j < 4; ++j) {
    int r = row0 + r8 + 32 * j;
    if constexpr (MODE == 1) {
      int tok = perm[r];
      ap[j] = A + (size_t)tok * 1024 + kc;
    } else if constexpr (MODE == 2) {
      ap[j] = A + (size_t)r * 4096 + kc;
    } else {
      ap[j] = A + (size_t)r * 1024 + kc;
    }
    int cb = bx * 128 + r8 + 32 * j;
    if constexpr (MODE == 0) bp[j] = Bm + (size_t)cb * 1024 + kc;
    else if constexpr (MODE == 1) bp[j] = Bm + ((size_t)e * 4096 + cb) * 1024 + kc;
    else bp[j] = Bm + ((size_t)e * 1024 + cb) * 4096 + kc;
  }

  const int w = t >> 6, lane = t & 63;
  const int wm = w >> 1, wn = w & 1;
  const int lr = lane & 15, lk = (lane >> 4) * 8;
  int aoffe[4], boffe[4];     // element offsets in LDS
#pragma unroll
  for (int i = 0; i < 4; ++i) {
    aoffe[i] = (wm * 64 + i * 16 + lr) * 64 + lk;
    boffe[i] = (wn * 64 + i * 16 + lr) * 64 + lk;
  }

  f32x4 acc[4][4];
#pragma unroll
  for (int i = 0; i < 4; ++i)
#pragma unroll
    for (int j = 0; j < 4; ++j) acc[i][j] = (f32x4)(0.f);

  ushort8 va[4], vb[4], va2[4], vb2[4];
#pragma unroll
  for (int j = 0; j < 4; ++j) {
    va[j] = *(const ushort8*)(ap[j]);
    vb[j] = *(const ushort8*)(bp[j]);
    if constexpr (SPLIT) {
      va2[j] = *(const ushort8*)(ap[j] + da);
      vb2[j] = *(const ushort8*)(bp[j] + db);
    }
    ap[j] += 64; bp[j] += 64;
  }

  for (int kt = 0; kt < KT; ++kt) {
    __syncthreads();
    {
      int so = t * 8;
#pragma unroll
      for (int j = 0; j < 4; ++j) {
        *(ushort8*)(lA + j * 2048 + so) = va[j];
        *(ushort8*)(lB + j * 2048 + so) = vb[j];
        if constexpr (SPLIT) {
          *(ushort8*)(lA + 8192 + j * 2048 + so) = va2[j];
          *(ushort8*)(lB + 8192 + j * 2048 + so) = vb2[j];
        }
      }
    }
    if (kt + 1 < KT) {
#pragma unroll
      for (int j = 0; j < 4; ++j) {
        va[j] = *(const ushort8*)(ap[j]);
        vb[j] = *(const ushort8*)(bp[j]);
        if constexpr (SPLIT) {
          va2[j] = *(const ushort8*)(ap[j] + da);
          vb2[j] = *(const ushort8*)(bp[j] + db);
        }
        ap[j] += 64; bp[j] += 64;
      }
    }
    __syncthreads();
#pragma unroll
    for (int kk = 0; kk < 2; ++kk) {
      short8 af[4], bfv[4], afl[4], bfl[4];
#pragma unroll
      for (int i = 0; i < 4; ++i) {
        af[i]  = *(const short8*)(lA + aoffe[i] + kk * 32);
        bfv[i] = *(const short8*)(lB + boffe[i] + kk * 32);
        if constexpr (SPLIT) {
          afl[i] = *(const short8*)(lA + 8192 + aoffe[i] + kk * 32);
          bfl[i] = *(const short8*)(lB + 8192 + boffe[i] + kk * 32);
        }
      }
#pragma unroll
      for (int mi = 0; mi < 4; ++mi)
#pragma unroll
        for (int ni = 0; ni < 4; ++ni) {
          acc[mi][ni] = __builtin_amdgcn_mfma_f32_16x16x32_bf16(af[mi], bfv[ni], acc[mi][ni], 0, 0, 0);
          if constexpr (SPLIT) {
            acc[mi][ni] = __builtin_amdgcn_mfma_f32_16x16x32_bf16(afl[mi], bfv[ni], acc[mi][ni], 0, 0, 0);
            acc[mi][ni] = __builtin_amdgcn_mfma_f32_16x16x32_bf16(af[mi], bfl[ni], acc[mi][ni], 0, 0, 0);
          }
        }
    }
  }

  // epilogue: C/D layout col=lane&15, row=(lane>>4)*4+q  [m89-verified]
#pragma unroll
  for (int mi = 0; mi < 4; ++mi) {
#pragma unroll
    for (int ni = 0; ni < 4; ++ni) {
      int col = bx * 128 + wn * 64 + ni * 16 + lr;
#pragma unroll
      for (int q = 0; q < 4; ++q) {
        int rl = wm * 64 + mi * 16 + (lane >> 4) * 4 + q;
        float v = acc[mi][ni][q];
        if constexpr (MODE == 0) {
          // fold biases + softplus(delta) here; skip dead pad cols
          if (col < 1056) {
            float v2;
            if (col < 1024) {
              float z = v + bias[col];
              v2 = fmaxf(z, 0.f) + __logf(1.f + __expf(-fabsf(z)));   // softplus
            } else if (col < 1040) {
              v2 = v + b1[col - 1024];
            } else {
              v2 = v + b2[col - 1040];
            }
            outF[(size_t)(row0 + rl) * NCP + col] = v2;
          }
        } else if constexpr (MODE == 1) {
          float z = v + bias[e * 4096 + col];
          float sg = 1.f / (1.f + __expf(-z));
          outH[(size_t)(row0 + rl) * 4096 + col] = f2bf(z * sg);
        } else {
          int pos = row0 + rl;
          if (pos < vend) {
            int tok = perm[pos];
            float val = (v + bias[e * 1024 + col]) * t1w[tok];
            outF[(size_t)tok * 1024 + col] = val;
          }
        }
      }
    }
  }
}

// ---------------- chunked selective scan ----------------
// h_t = barA_t * h_{t-1} + barB_t * x_t is LINEAR in h (clip at +-100 never
// fires at these scales: |h| <= ~10). 16 chunks x 128 steps:
//   pass1: per-chunk A_prod + h_end(from 0);  pass2: 16-step combine;
//   pass3: re-scan from true h_init, emit y.
constexpr int SPF = 4;

template<int PASS>
__global__ __launch_bounds__(256) void scan_p(
    const float* __restrict__ P, const float* __restrict__ x,
    const float* __restrict__ A_log, const float* __restrict__ D_param,
    float* __restrict__ Ap, float* __restrict__ He, const float* __restrict__ Hi,
    float* __restrict__ ssm, unsigned short* __restrict__ ssmbf)
{
  const int t = threadIdx.x;
  const int s = t & 15, dlane = t >> 4;
  const int blk = blockIdx.x;
  const int c  = blk & 15;
  const int dg = (blk >> 4) & 63;
  const int b  = blk >> 10;
  const int d  = dg * 16 + dlane;
  const float Ads = -__expf(A_log[d * 16 + s]);
  const float Dp = D_param[d];
  const float* Pb = P + ((size_t)b * 2048 + (size_t)c * CLEN) * NCP;
  const float* xb = x + ((size_t)b * 2048 + (size_t)c * CLEN) * 1024;
  const size_t sidx = (size_t)c * 65536 + ((size_t)b * 1024 + d) * 16 + s;

  float h = (PASS == 1) ? 0.f : Hi[sidx];
  float ap = 1.f;

  float dl0[SPF], br0[SPF], cr0[SPF], xr0[SPF];
  auto LOADB = [&](int base, float* dd, float* bb, float* cc2, float* xx) {
#pragma unroll
    for (int j = 0; j < SPF; ++j) {
      const float* Pt = Pb + (size_t)(base + j) * NCP;
      dd[j] = Pt[d];                 // delta (softplus pre-applied)
      bb[j] = Pt[1024 + s];          // B + bB
      if constexpr (PASS == 3) cc2[j] = Pt[1040 + s];   // C + bC
      xx[j] = xb[(size_t)(base + j) * 1024 + d];
    }
  };
  LOADB(0, dl0, br0, cr0, xr0);
  size_t obase = ((size_t)b * 2048 + (size_t)c * CLEN) * 1024 + d;
  constexpr int NBAT = CLEN / SPF;
  for (int bb = 0; bb < NBAT; ++bb) {
    float dl1[SPF], br1[SPF], cr1[SPF], xr1[SPF];
    if (bb + 1 < NBAT) LOADB((bb + 1) * SPF, dl1, br1, cr1, xr1);
#pragma unroll
    for (int j = 0; j < SPF; ++j) {
      float delta = dl0[j];
      float barA = __expf(delta * Ads);          // dA<=0 always, min(.,2) is a no-op
      float barB = fminf(fmaxf(delta * br0[j], -2.f), 2.f);
      h = fminf(fmaxf(barA * h + barB * xr0[j], -100.f), 100.f);
      if constexpr (PASS == 1) {
        ap *= barA;
      } else {
        float y = h * cr0[j];
        y += __shfl_xor(y, 1); y += __shfl_xor(y, 2);
        y += __shfl_xor(y, 4); y += __shfl_xor(y, 8);
        if (s == 0) {
          float val = y + xr0[j] * Dp;
          size_t o = obase + (size_t)(bb * SPF + j) * 1024;
          ssm[o] = val;
          ssmbf[o] = f2bf(val);
        }
      }
    }
    if (bb + 1 < NBAT) {
#pragma unroll
      for (int j = 0; j < SPF; ++j) { dl0[j]=dl1[j]; br0[j]=br1[j]; cr0[j]=cr1[j]; xr0[j]=xr1[j]; }
    }
  }
  if constexpr (PASS == 1) {
    Ap[sidx] = ap;
    He[sidx] = h;
  }
}

__global__ __launch_bounds__(256) void scan_c(const float* __restrict__ Ap,
    const float* __restrict__ He, float* __restrict__ Hi)
{
  int i = blockIdx.x * 256 + threadIdx.x;   // 65536 = (b*1024+d)*16+s
  float h = 0.f;
#pragma unroll
  for (int c = 0; c < NCHUNK; ++c) {
    size_t idx = (size_t)c * 65536 + i;
    Hi[idx] = h;
    h = Ap[idx] * h + He[idx];
  }
}

// ---------------- routing ----------------
__global__ __launch_bounds__(256) void route_k(
    const float* __restrict__ ssm, const float* __restrict__ Wr, const float* __restrict__ br,
    float* __restrict__ t1w, int* __restrict__ t1i, int* __restrict__ counts)
{
  int w = threadIdx.x >> 6, lane = threadIdx.x & 63;
  int n = blockIdx.x * 4 + w;
  const float* row = ssm + (size_t)n * 1024;
  float a0 = 0, a1 = 0, a2 = 0, a3 = 0;
  for (int i = lane; i < 1024; i += 64) {
    float v = row[i];
    f32x4 wr = *(const f32x4*)(Wr + i * 4);
    a0 += v * wr[0]; a1 += v * wr[1]; a2 += v * wr[2]; a3 += v * wr[3];
  }
#pragma unroll
  for (int off = 32; off; off >>= 1) {
    a0 += __shfl_xor(a0, off); a1 += __shfl_xor(a1, off);
    a2 += __shfl_xor(a2, off); a3 += __shfl_xor(a3, off);
  }
  a0 += br[0]; a1 += br[1]; a2 += br[2]; a3 += br[3];
  float m = a0; int idx = 0;
  if (a1 > m) { m = a1; idx = 1; }
  if (a2 > m) { m = a2; idx = 2; }
  if (a3 > m) { m = a3; idx = 3; }
  float denom = __expf(a0 - m) + __expf(a1 - m) + __expf(a2 - m) + __expf(a3 - m);
  if (lane == 0) {
    t1w[n] = 1.f / denom;
    t1i[n] = idx;
    atomicAdd(&counts[idx], 1);
  }
}

// misc layout (ints): counts@0 cursors@4 base@8 ntiles@12 tile_e@16 tile_r0@96 tile_ve@176
__global__ void build_k(int* misc, int* perm)
{
  if (threadIdx.x != 0 || blockIdx.x != 0) return;
  int* counts = misc; int* cursors = misc + 4; int* base = misc + 8;
  int* ntiles = misc + 12; int* te = misc + 16; int* tr = misc + 96; int* tv = misc + 176;
  int bpos = 0, tt = 0;
  for (int e = 0; e < 4; ++e) {
    base[e] = bpos; cursors[e] = 0;
    int c = counts[e];
    int nt = (c + 127) >> 7;
    for (int i = 0; i < nt; ++i) { te[tt] = e; tr[tt] = bpos + i * 128; tv[tt] = bpos + c; ++tt; }
    for (int p = bpos + c; p < bpos + nt * 128; ++p) perm[p] = 0;
    bpos += nt * 128;
  }
  *ntiles = tt;
}

__global__ __launch_bounds__(256) void scatter_k(const int* __restrict__ t1i,
    int* misc, int* __restrict__ perm)
{
  int n = blockIdx.x * 256 + threadIdx.x;
  int e = t1i[n];
  int pos = atomicAdd(&misc[4 + e], 1);
  perm[misc[8 + e] + pos] = n;
}

// ---------------- add + layernorm (in place on d_out) ----------------
__global__ __launch_bounds__(256) void ln_k(
    float* __restrict__ out, const float* __restrict__ ssm,
    const float* __restrict__ lnw, const float* __restrict__ lnb)
{
  __shared__ float red[8];
  int n = blockIdx.x, t = threadIdx.x;
  size_t base = (size_t)n * 1024 + t * 4;
  f32x4 a = *(const f32x4*)(out + base);
  f32x4 bsm = *(const f32x4*)(ssm + base);
  float o[4]; float sum = 0, sq = 0;
#pragma unroll
  for (int j = 0; j < 4; ++j) { o[j] = a[j] + bsm[j]; sum += o[j]; sq += o[j] * o[j]; }
#pragma unroll
  for (int off = 32; off; off >>= 1) { sum += __shfl_xor(sum, off); sq += __shfl_xor(sq, off); }
  int w = t >> 6;
  if ((t & 63) == 0) { red[w] = sum; red[4 + w] = sq; }
  __syncthreads();
  sum = red[0] + red[1] + red[2] + red[3];
  sq  = red[4] + red[5] + red[6] + red[7];
  float mu = sum * (1.f / 1024.f);
  float var = sq * (1.f / 1024.f) - mu * mu;
  float rs = rsqrtf(var + 1e-5f);
  f32x4 r;
#pragma unroll
  for (int j = 0; j < 4; ++j) {
    int c = t * 4 + j;
    r[j] = (o[j] - mu) * rs * lnw[c] + lnb[c];
  }
  *(f32x4*)(out + base) = r;
}

// ---------------- launch ----------------
extern "C" void kernel_launch(void* const* d_in, const int* in_sizes, int n_in,
                              void* d_out, int out_size, void* d_ws, size_t ws_size,
                              hipStream_t stream)
{
  (void)in_sizes; (void)n_in; (void)out_size;
  const float* x       = (const float*)d_in[0];
  const float* A_log   = (const float*)d_in[1];
  const float* D_param = (const float*)d_in[2];
  const float* Wd      = (const float*)d_in[3];
  const float* bd      = (const float*)d_in[4];
  const float* WB      = (const float*)d_in[5];
  const float* bB      = (const float*)d_in[6];
  const float* WC      = (const float*)d_in[7];
  const float* bC      = (const float*)d_in[8];
  const float* Wr      = (const float*)d_in[9];
  const float* br      = (const float*)d_in[10];
  const float* up_w    = (const float*)d_in[11];
  const float* up_b    = (const float*)d_in[12];
  const float* down_w  = (const float*)d_in[13];
  const float* down_b  = (const float*)d_in[14];
  const float* ln_w    = (const float*)d_in[15];
  const float* ln_b    = (const float*)d_in[16];
  float* out = (float*)d_out;

  char* ws = (char*)d_ws;
  size_t off = 0;
  auto alloc = [&](size_t bytes) { size_t o = off; off += (bytes + 255) & ~(size_t)255; return o; };
  size_t oXh  = alloc((size_t)NTOK * 1024 * 2);
  size_t oXl  = alloc((size_t)NTOK * 1024 * 2);
  size_t oWh  = alloc((size_t)NCP * 1024 * 2);
  size_t oWl  = alloc((size_t)NCP * 1024 * 2);
  size_t oP   = alloc((size_t)NTOK * NCP * 4);
  size_t oSSM = alloc((size_t)NTOK * 1024 * 4);
  size_t oSBF = alloc((size_t)NTOK * 1024 * 2);
  size_t oUp  = alloc((size_t)4 * 4096 * 1024 * 2);
  size_t oDn  = alloc((size_t)4 * 4096 * 1024 * 2);
  size_t oHid = alloc((size_t)NPAD * 4096 * 2);   // ALSO hosts scan Ap/He/Hi (12.6MB):
                                                  // they are dead before gemm<1> writes Hid
  size_t oT1w = alloc((size_t)NTOK * 4);
  size_t oT1i = alloc((size_t)NTOK * 4);
  size_t oPerm= alloc((size_t)NPAD * 4);
  size_t oMisc= alloc(1024);
  if (ws_size < off) return;   // distinctive failure: absmax == stub's 8.5

  unsigned short* Xh  = (unsigned short*)(ws + oXh);
  unsigned short* Xl  = (unsigned short*)(ws + oXl);
  unsigned short* Wh  = (unsigned short*)(ws + oWh);
  unsigned short* Wl  = (unsigned short*)(ws + oWl);
  float*          Pf  = (float*)(ws + oP);
  float*          SSM = (float*)(ws + oSSM);
  unsigned short* SBF = (unsigned short*)(ws + oSBF);
  unsigned short* UpT = (unsigned short*)(ws + oUp);
  unsigned short* DnT = (unsigned short*)(ws + oDn);
  unsigned short* Hid = (unsigned short*)(ws + oHid);
  float*          T1w = (float*)(ws + oT1w);
  int*            T1i = (int*)(ws + oT1i);
  int*            perm= (int*)(ws + oPerm);
  int*            misc= (int*)(ws + oMisc);
  // scan scratch aliased into the (not-yet-live) Hid region:
  float*          ApB = (float*)(ws + oHid);
  float*          HeB = ApB + (size_t)NCHUNK * 65536;
  float*          HiB = HeB + (size_t)NCHUNK * 65536;

  hipMemsetAsync(misc, 0, 16, stream);                         // counts = 0
  conv_x_k <<<8192, 256, 0, stream>>>(x, Xh, Xl);
  conv_w_k <<<4608, 256, 0, stream>>>(Wd, WB, WC, Wh, Wl);
  trans_k<<<dim3(128, 32, 4), 256, 0, stream>>>(up_w, UpT, 1024, 4096);   // [e][d][f]->[e][f][d]
  trans_k<<<dim3(32, 128, 4), 256, 0, stream>>>(down_w, DnT, 4096, 1024); // [e][f][d]->[e][d][f]

  gemm_k<0><<<dim3(9, 64), 256, 0, stream>>>(Xh, Xl, Wh, Wl, Pf, nullptr,
      bd, bB, bC, nullptr, nullptr, nullptr, nullptr, nullptr, nullptr);

  scan_p<1><<<4096, 256, 0, stream>>>(Pf, x, A_log, D_param, ApB, HeB, nullptr, nullptr, nullptr);
  scan_c   <<<256, 256, 0, stream>>>(ApB, HeB, HiB);
  scan_p<3><<<4096, 256, 0, stream>>>(Pf, x, A_log, D_param, nullptr, nullptr, HiB, SSM, SBF);

  route_k<<<2048, 256, 0, stream>>>(SSM, Wr, br, T1w, T1i, misc);
  build_k<<<1, 1, 0, stream>>>(misc, perm);
  scatter_k<<<32, 256, 0, stream>>>(T1i, misc, perm);

  gemm_k<1><<<dim3(32, MAXTILES), 256, 0, stream>>>(SBF, nullptr, UpT, nullptr,
      nullptr, Hid, up_b, nullptr, nullptr, perm, nullptr, misc + 16, misc + 96, misc + 176, misc + 12);
  gemm_k<2><<<dim3(8, MAXTILES), 256, 0, stream>>>(Hid, nullptr, DnT, nullptr,
      out, nullptr, down_b, nullptr, nullptr, perm, T1w, misc + 16, misc + 96, misc + 176, misc + 12);

  ln_k<<<8192, 256, 0, stream>>>(out, SSM, ln_w, ln_b);
}

// Round 4
// 899.691 us; speedup vs baseline: 1.9867x; 1.0194x over previous
//
#include <hip/hip_runtime.h>

typedef __attribute__((ext_vector_type(4))) float f32x4;
typedef __attribute__((ext_vector_type(8))) short short8;
typedef __attribute__((ext_vector_type(8))) unsigned short ushort8;
typedef __attribute__((ext_vector_type(4))) unsigned short ushort4v;

#define DEV __device__ __forceinline__

constexpr int NTOK = 8192;       // B*L
constexpr int NCP  = 1152;       // padded proj out cols (1024 delta | 16 B | 16 C | 96 pad)
constexpr int MAXTILES = 68;
constexpr int NPAD = MAXTILES * 128;
constexpr int NCHUNK = 16;
constexpr int CLEN = 2048 / NCHUNK;   // 128

DEV unsigned short f2bf(float f) {
  unsigned int u = __builtin_bit_cast(unsigned int, f);
  u += 0x7FFFu + ((u >> 16) & 1u);
  return (unsigned short)(u >> 16);
}
DEV float bf2f(unsigned short h) {
  unsigned int u = ((unsigned int)h) << 16;
  return __builtin_bit_cast(float, u);
}

// async global->LDS, 16B per lane; LDS dest is wave-uniform base + lane*16 [m97/m104]
DEV void gload16(const unsigned short* g, unsigned short* l) {
  __builtin_amdgcn_global_load_lds(
      (const __attribute__((address_space(1))) unsigned int*)g,
      (__attribute__((address_space(3))) unsigned int*)l, 16, 0, 0);
}

// ---------------- conversions ----------------
__global__ __launch_bounds__(256) void conv_x_k(const float* __restrict__ x,
    unsigned short* __restrict__ xh, unsigned short* __restrict__ xl) {
  int i = (blockIdx.x * 256 + threadIdx.x) * 4;
  f32x4 v = *(const f32x4*)(x + i);
  ushort4v hv, lv;
#pragma unroll
  for (int j = 0; j < 4; ++j) {
    unsigned short hh = f2bf(v[j]);
    hv[j] = hh;
    lv[j] = f2bf(v[j] - bf2f(hh));
  }
  *(ushort4v*)(xh + i) = hv;
  *(ushort4v*)(xl + i) = lv;
}

__global__ __launch_bounds__(256) void conv_w_k(const float* __restrict__ Wd,
    const float* __restrict__ WB, const float* __restrict__ WC,
    unsigned short* __restrict__ wh, unsigned short* __restrict__ wl) {
  int o = blockIdx.x * 256 + threadIdx.x;   // NCP*1024 total, layout [n][k]
  int k = o & 1023, n = o >> 10;
  float v = 0.f;
  if (n < 1024) v = Wd[k * 1024 + n];
  else if (n < 1040) v = WB[k * 16 + (n - 1024)];
  else if (n < 1056) v = WC[k * 16 + (n - 1040)];
  unsigned short hh = f2bf(v);
  wh[o] = hh;
  wl[o] = f2bf(v - bf2f(hh));
}

// LDS-tiled transpose + f32->bf16: in [E][R][C] -> out [E][C][R]
__global__ __launch_bounds__(256) void trans_k(const float* __restrict__ in,
    unsigned short* __restrict__ out, int R, int C) {
  __shared__ float tile[32][33];
  int e = blockIdx.z;
  int r0 = blockIdx.y * 32, c0 = blockIdx.x * 32;
  int r = threadIdx.x >> 5, cc = threadIdx.x & 31;
  const float* src = in + ((size_t)e * R + r0) * C + c0;
#pragma unroll
  for (int j = 0; j < 4; ++j) tile[r + j * 8][cc] = src[(size_t)(r + j * 8) * C + cc];
  __syncthreads();
  unsigned short* dst = out + ((size_t)e * C + c0) * R + r0;
#pragma unroll
  for (int j = 0; j < 4; ++j) dst[(size_t)(r + j * 8) * R + cc] = f2bf(tile[cc][r + j * 8]);
}

// ---------------- GEMM (MODE 0: split proj, 1: up+silu, 2: down+scatter) ----------------
// m97 structure: single LDS buffer, global_load_lds width-16 staging, 2 barriers/K-step.
template<int MODE>
__global__ __launch_bounds__(256) void gemm_k(
    const unsigned short* __restrict__ A, const unsigned short* __restrict__ A2,
    const unsigned short* __restrict__ Bm, const unsigned short* __restrict__ B2,
    float* __restrict__ outF, unsigned short* __restrict__ outH,
    const float* __restrict__ bias, const float* __restrict__ b1, const float* __restrict__ b2,
    const int* __restrict__ perm, const float* __restrict__ t1w,
    const int* __restrict__ tile_e, const int* __restrict__ tile_r0,
    const int* __restrict__ tile_ve, const int* __restrict__ n_tiles)
{
  constexpr int K = (MODE == 2) ? 4096 : 1024;
  constexpr int KT = K / 64;
  constexpr bool SPLIT = (MODE == 0);
  __shared__ __align__(16) unsigned short lA[(SPLIT ? 2 : 1) * 128 * 64];
  __shared__ __align__(16) unsigned short lB[(SPLIT ? 2 : 1) * 128 * 64];

  const int t = threadIdx.x;
  const int bx = blockIdx.x;
  const int by = blockIdx.y;
  int e = 0, row0 = 0, vend = 0;
  if constexpr (MODE == 0) {
    row0 = by * 128;
  } else {
    if (by >= *n_tiles) return;
    e = tile_e[by]; row0 = tile_r0[by]; vend = tile_ve[by];
  }
  (void)vend;

  const int w = t >> 6, lane = t & 63;
  // staging geometry: chunk c covers LDS bytes [w*4096 + c*1024); this lane
  // holds row w*32 + c*8 + (lane>>3), col elems (lane&7)*8 .. +8
  const int srow = w * 32 + (lane >> 3);      // + c*8
  const int scol = (lane & 7) * 8;
  const unsigned short* ap[4];
  const unsigned short* bp[4];
  ptrdiff_t da = 0, db = 0;
  if constexpr (SPLIT) { da = A2 - A; db = B2 - Bm; }
#pragma unroll
  for (int c = 0; c < 4; ++c) {
    int r = row0 + srow + c * 8;
    if constexpr (MODE == 1) {
      int tok = perm[r];
      ap[c] = A + (size_t)tok * 1024 + scol;
    } else if constexpr (MODE == 2) {
      ap[c] = A + (size_t)r * 4096 + scol;
    } else {
      ap[c] = A + (size_t)r * 1024 + scol;
    }
    int cb = bx * 128 + srow + c * 8;
    if constexpr (MODE == 0) bp[c] = Bm + (size_t)cb * 1024 + scol;
    else if constexpr (MODE == 1) bp[c] = Bm + ((size_t)e * 4096 + cb) * 1024 + scol;
    else bp[c] = Bm + ((size_t)e * 1024 + cb) * 4096 + scol;
  }

  const int wm = w >> 1, wn = w & 1;
  const int lr = lane & 15, lk = (lane >> 4) * 8;
  int aoffe[4], boffe[4];     // element offsets in LDS
#pragma unroll
  for (int i = 0; i < 4; ++i) {
    aoffe[i] = (wm * 64 + i * 16 + lr) * 64 + lk;
    boffe[i] = (wn * 64 + i * 16 + lr) * 64 + lk;
  }

  f32x4 acc[4][4];
#pragma unroll
  for (int i = 0; i < 4; ++i)
#pragma unroll
    for (int j = 0; j < 4; ++j) acc[i][j] = (f32x4)(0.f);

  for (int kt = 0; kt < KT; ++kt) {
    __syncthreads();   // prior compute's ds_reads drained (compiler: waitcnt before barrier)
#pragma unroll
    for (int c = 0; c < 4; ++c) {
      unsigned short* ldst = lA + w * 2048 + c * 512;
      unsigned short* ldst2 = lB + w * 2048 + c * 512;
      gload16(ap[c], ldst);
      gload16(bp[c], ldst2);
      if constexpr (SPLIT) {
        gload16(ap[c] + da, ldst + 8192);
        gload16(bp[c] + db, ldst2 + 8192);
      }
      ap[c] += 64; bp[c] += 64;
    }
    __syncthreads();   // loads landed (compiler: vmcnt(0) before barrier)
#pragma unroll
    for (int kk = 0; kk < 2; ++kk) {
      short8 af[4], bfv[4], afl[4], bfl[4];
#pragma unroll
      for (int i = 0; i < 4; ++i) {
        af[i]  = *(const short8*)(lA + aoffe[i] + kk * 32);
        bfv[i] = *(const short8*)(lB + boffe[i] + kk * 32);
        if constexpr (SPLIT) {
          afl[i] = *(const short8*)(lA + 8192 + aoffe[i] + kk * 32);
          bfl[i] = *(const short8*)(lB + 8192 + boffe[i] + kk * 32);
        }
      }
#pragma unroll
      for (int mi = 0; mi < 4; ++mi)
#pragma unroll
        for (int ni = 0; ni < 4; ++ni) {
          acc[mi][ni] = __builtin_amdgcn_mfma_f32_16x16x32_bf16(af[mi], bfv[ni], acc[mi][ni], 0, 0, 0);
          if constexpr (SPLIT) {
            acc[mi][ni] = __builtin_amdgcn_mfma_f32_16x16x32_bf16(afl[mi], bfv[ni], acc[mi][ni], 0, 0, 0);
            acc[mi][ni] = __builtin_amdgcn_mfma_f32_16x16x32_bf16(af[mi], bfl[ni], acc[mi][ni], 0, 0, 0);
          }
        }
    }
  }

  // epilogue: C/D layout col=lane&15, row=(lane>>4)*4+q  [m89-verified]
#pragma unroll
  for (int mi = 0; mi < 4; ++mi) {
#pragma unroll
    for (int ni = 0; ni < 4; ++ni) {
      int col = bx * 128 + wn * 64 + ni * 16 + lr;
#pragma unroll
      for (int q = 0; q < 4; ++q) {
        int rl = wm * 64 + mi * 16 + (lane >> 4) * 4 + q;
        float v = acc[mi][ni][q];
        if constexpr (MODE == 0) {
          // fold biases + softplus(delta) here; skip dead pad cols
          if (col < 1056) {
            float v2;
            if (col < 1024) {
              float z = v + bias[col];
              v2 = fmaxf(z, 0.f) + __logf(1.f + __expf(-fabsf(z)));   // softplus
            } else if (col < 1040) {
              v2 = v + b1[col - 1024];
            } else {
              v2 = v + b2[col - 1040];
            }
            outF[(size_t)(row0 + rl) * NCP + col] = v2;
          }
        } else if constexpr (MODE == 1) {
          float z = v + bias[e * 4096 + col];
          float sg = 1.f / (1.f + __expf(-z));
          outH[(size_t)(row0 + rl) * 4096 + col] = f2bf(z * sg);
        } else {
          int pos = row0 + rl;
          if (pos < vend) {
            int tok = perm[pos];
            float val = (v + bias[e * 1024 + col]) * t1w[tok];
            outF[(size_t)tok * 1024 + col] = val;
          }
        }
      }
    }
  }
}

// ---------------- chunked selective scan ----------------
// h_t = barA_t * h_{t-1} + barB_t * x_t is LINEAR in h (clip at +-100 never
// fires at these scales: |h| <= ~10). 16 chunks x 128 steps:
//   pass1: per-chunk A_prod + h_end(from 0);  pass2: 16-step combine;
//   pass3: re-scan with true h_init + emit y.
constexpr int SPF = 4;

template<int PASS>
__global__ __launch_bounds__(256) void scan_p(
    const float* __restrict__ P, const float* __restrict__ x,
    const float* __restrict__ A_log, const float* __restrict__ D_param,
    float* __restrict__ Ap, float* __restrict__ He, const float* __restrict__ Hi,
    float* __restrict__ ssm, unsigned short* __restrict__ ssmbf)
{
  const int t = threadIdx.x;
  const int s = t & 15, dlane = t >> 4;
  const int blk = blockIdx.x;
  const int c  = blk & 15;
  const int dg = (blk >> 4) & 63;
  const int b  = blk >> 10;
  const int d  = dg * 16 + dlane;
  const float Ads = -__expf(A_log[d * 16 + s]);
  const float Dp = D_param[d];
  const float* Pb = P + ((size_t)b * 2048 + (size_t)c * CLEN) * NCP;
  const float* xb = x + ((size_t)b * 2048 + (size_t)c * CLEN) * 1024;
  const size_t sidx = (size_t)c * 65536 + ((size_t)b * 1024 + d) * 16 + s;

  float h = (PASS == 1) ? 0.f : Hi[sidx];
  float ap = 1.f;

  float dl0[SPF], br0[SPF], cr0[SPF], xr0[SPF];
  auto LOADB = [&](int base, float* dd, float* bb, float* cc2, float* xx) {
#pragma unroll
    for (int j = 0; j < SPF; ++j) {
      const float* Pt = Pb + (size_t)(base + j) * NCP;
      dd[j] = Pt[d];                 // delta (softplus pre-applied)
      bb[j] = Pt[1024 + s];          // B + bB
      if constexpr (PASS == 3) cc2[j] = Pt[1040 + s];   // C + bC
      xx[j] = xb[(size_t)(base + j) * 1024 + d];
    }
  };
  LOADB(0, dl0, br0, cr0, xr0);
  size_t obase = ((size_t)b * 2048 + (size_t)c * CLEN) * 1024 + d;
  constexpr int NBAT = CLEN / SPF;
  for (int bb = 0; bb < NBAT; ++bb) {
    float dl1[SPF], br1[SPF], cr1[SPF], xr1[SPF];
    if (bb + 1 < NBAT) LOADB((bb + 1) * SPF, dl1, br1, cr1, xr1);
#pragma unroll
    for (int j = 0; j < SPF; ++j) {
      float delta = dl0[j];
      float barA = __expf(delta * Ads);          // dA<=0 always, min(.,2) is a no-op
      float barB = fminf(fmaxf(delta * br0[j], -2.f), 2.f);
      h = fminf(fmaxf(barA * h + barB * xr0[j], -100.f), 100.f);
      if constexpr (PASS == 1) {
        ap *= barA;
      } else {
        float y = h * cr0[j];
        y += __shfl_xor(y, 1); y += __shfl_xor(y, 2);
        y += __shfl_xor(y, 4); y += __shfl_xor(y, 8);
        if (s == 0) {
          float val = y + xr0[j] * Dp;
          size_t o = obase + (size_t)(bb * SPF + j) * 1024;
          ssm[o] = val;
          ssmbf[o] = f2bf(val);
        }
      }
    }
    if (bb + 1 < NBAT) {
#pragma unroll
      for (int j = 0; j < SPF; ++j) { dl0[j]=dl1[j]; br0[j]=br1[j]; cr0[j]=cr1[j]; xr0[j]=xr1[j]; }
    }
  }
  if constexpr (PASS == 1) {
    Ap[sidx] = ap;
    He[sidx] = h;
  }
}

__global__ __launch_bounds__(256) void scan_c(const float* __restrict__ Ap,
    const float* __restrict__ He, float* __restrict__ Hi)
{
  int i = blockIdx.x * 256 + threadIdx.x;   // 65536 = (b*1024+d)*16+s
  float h = 0.f;
#pragma unroll
  for (int c = 0; c < NCHUNK; ++c) {
    size_t idx = (size_t)c * 65536 + i;
    Hi[idx] = h;
    h = Ap[idx] * h + He[idx];
  }
}

// ---------------- routing ----------------
__global__ __launch_bounds__(256) void route_k(
    const float* __restrict__ ssm, const float* __restrict__ Wr, const float* __restrict__ br,
    float* __restrict__ t1w, int* __restrict__ t1i, int* __restrict__ counts)
{
  int w = threadIdx.x >> 6, lane = threadIdx.x & 63;
  int n = blockIdx.x * 4 + w;
  const float* row = ssm + (size_t)n * 1024;
  float a0 = 0, a1 = 0, a2 = 0, a3 = 0;
  for (int i = lane; i < 1024; i += 64) {
    float v = row[i];
    f32x4 wr = *(const f32x4*)(Wr + i * 4);
    a0 += v * wr[0]; a1 += v * wr[1]; a2 += v * wr[2]; a3 += v * wr[3];
  }
#pragma unroll
  for (int off = 32; off; off >>= 1) {
    a0 += __shfl_xor(a0, off); a1 += __shfl_xor(a1, off);
    a2 += __shfl_xor(a2, off); a3 += __shfl_xor(a3, off);
  }
  a0 += br[0]; a1 += br[1]; a2 += br[2]; a3 += br[3];
  float m = a0; int idx = 0;
  if (a1 > m) { m = a1; idx = 1; }
  if (a2 > m) { m = a2; idx = 2; }
  if (a3 > m) { m = a3; idx = 3; }
  float denom = __expf(a0 - m) + __expf(a1 - m) + __expf(a2 - m) + __expf(a3 - m);
  if (lane == 0) {
    t1w[n] = 1.f / denom;
    t1i[n] = idx;
    atomicAdd(&counts[idx], 1);
  }
}

// misc layout (ints): counts@0 cursors@4 base@8 ntiles@12 tile_e@16 tile_r0@96 tile_ve@176
__global__ void build_k(int* misc, int* perm)
{
  if (threadIdx.x != 0 || blockIdx.x != 0) return;
  int* counts = misc; int* cursors = misc + 4; int* base = misc + 8;
  int* ntiles = misc + 12; int* te = misc + 16; int* tr = misc + 96; int* tv = misc + 176;
  int bpos = 0, tt = 0;
  for (int e = 0; e < 4; ++e) {
    base[e] = bpos; cursors[e] = 0;
    int c = counts[e];
    int nt = (c + 127) >> 7;
    for (int i = 0; i < nt; ++i) { te[tt] = e; tr[tt] = bpos + i * 128; tv[tt] = bpos + c; ++tt; }
    for (int p = bpos + c; p < bpos + nt * 128; ++p) perm[p] = 0;
    bpos += nt * 128;
  }
  *ntiles = tt;
}

__global__ __launch_bounds__(256) void scatter_k(const int* __restrict__ t1i,
    int* misc, int* __restrict__ perm)
{
  int n = blockIdx.x * 256 + threadIdx.x;
  int e = t1i[n];
  int pos = atomicAdd(&misc[4 + e], 1);
  perm[misc[8 + e] + pos] = n;
}

// ---------------- add + layernorm (in place on d_out) ----------------
__global__ __launch_bounds__(256) void ln_k(
    float* __restrict__ out, const float* __restrict__ ssm,
    const float* __restrict__ lnw, const float* __restrict__ lnb)
{
  __shared__ float red[8];
  int n = blockIdx.x, t = threadIdx.x;
  size_t base = (size_t)n * 1024 + t * 4;
  f32x4 a = *(const f32x4*)(out + base);
  f32x4 bsm = *(const f32x4*)(ssm + base);
  float o[4]; float sum = 0, sq = 0;
#pragma unroll
  for (int j = 0; j < 4; ++j) { o[j] = a[j] + bsm[j]; sum += o[j]; sq += o[j] * o[j]; }
#pragma unroll
  for (int off = 32; off; off >>= 1) { sum += __shfl_xor(sum, off); sq += __shfl_xor(sq, off); }
  int w = t >> 6;
  if ((t & 63) == 0) { red[w] = sum; red[4 + w] = sq; }
  __syncthreads();
  sum = red[0] + red[1] + red[2] + red[3];
  sq  = red[4] + red[5] + red[6] + red[7];
  float mu = sum * (1.f / 1024.f);
  float var = sq * (1.f / 1024.f) - mu * mu;
  float rs = rsqrtf(var + 1e-5f);
  f32x4 r;
#pragma unroll
  for (int j = 0; j < 4; ++j) {
    int c = t * 4 + j;
    r[j] = (o[j] - mu) * rs * lnw[c] + lnb[c];
  }
  *(f32x4*)(out + base) = r;
}

// ---------------- launch ----------------
extern "C" void kernel_launch(void* const* d_in, const int* in_sizes, int n_in,
                              void* d_out, int out_size, void* d_ws, size_t ws_size,
                              hipStream_t stream)
{
  (void)in_sizes; (void)n_in; (void)out_size;
  const float* x       = (const float*)d_in[0];
  const float* A_log   = (const float*)d_in[1];
  const float* D_param = (const float*)d_in[2];
  const float* Wd      = (const float*)d_in[3];
  const float* bd      = (const float*)d_in[4];
  const float* WB      = (const float*)d_in[5];
  const float* bB      = (const float*)d_in[6];
  const float* WC      = (const float*)d_in[7];
  const float* bC      = (const float*)d_in[8];
  const float* Wr      = (const float*)d_in[9];
  const float* br      = (const float*)d_in[10];
  const float* up_w    = (const float*)d_in[11];
  const float* up_b    = (const float*)d_in[12];
  const float* down_w  = (const float*)d_in[13];
  const float* down_b  = (const float*)d_in[14];
  const float* ln_w    = (const float*)d_in[15];
  const float* ln_b    = (const float*)d_in[16];
  float* out = (float*)d_out;

  char* ws = (char*)d_ws;
  size_t off = 0;
  auto alloc = [&](size_t bytes) { size_t o = off; off += (bytes + 255) & ~(size_t)255; return o; };
  size_t oXh  = alloc((size_t)NTOK * 1024 * 2);
  size_t oXl  = alloc((size_t)NTOK * 1024 * 2);
  size_t oWh  = alloc((size_t)NCP * 1024 * 2);
  size_t oWl  = alloc((size_t)NCP * 1024 * 2);
  size_t oP   = alloc((size_t)NTOK * NCP * 4);
  size_t oSSM = alloc((size_t)NTOK * 1024 * 4);
  size_t oSBF = alloc((size_t)NTOK * 1024 * 2);
  size_t oUp  = alloc((size_t)4 * 4096 * 1024 * 2);
  size_t oDn  = alloc((size_t)4 * 4096 * 1024 * 2);
  size_t oHid = alloc((size_t)NPAD * 4096 * 2);   // ALSO hosts scan Ap/He/Hi (12.6MB):
                                                  // they are dead before gemm<1> writes Hid
  size_t oT1w = alloc((size_t)NTOK * 4);
  size_t oT1i = alloc((size_t)NTOK * 4);
  size_t oPerm= alloc((size_t)NPAD * 4);
  size_t oMisc= alloc(1024);
  if (ws_size < off) return;   // distinctive failure: absmax == stub's 8.5

  unsigned short* Xh  = (unsigned short*)(ws + oXh);
  unsigned short* Xl  = (unsigned short*)(ws + oXl);
  unsigned short* Wh  = (unsigned short*)(ws + oWh);
  unsigned short* Wl  = (unsigned short*)(ws + oWl);
  float*          Pf  = (float*)(ws + oP);
  float*          SSM = (float*)(ws + oSSM);
  unsigned short* SBF = (unsigned short*)(ws + oSBF);
  unsigned short* UpT = (unsigned short*)(ws + oUp);
  unsigned short* DnT = (unsigned short*)(ws + oDn);
  unsigned short* Hid = (unsigned short*)(ws + oHid);
  float*          T1w = (float*)(ws + oT1w);
  int*            T1i = (int*)(ws + oT1i);
  int*            perm= (int*)(ws + oPerm);
  int*            misc= (int*)(ws + oMisc);
  // scan scratch aliased into the (not-yet-live) Hid region:
  float*          ApB = (float*)(ws + oHid);
  float*          HeB = ApB + (size_t)NCHUNK * 65536;
  float*          HiB = HeB + (size_t)NCHUNK * 65536;

  hipMemsetAsync(misc, 0, 16, stream);                         // counts = 0
  conv_x_k <<<8192, 256, 0, stream>>>(x, Xh, Xl);
  conv_w_k <<<4608, 256, 0, stream>>>(Wd, WB, WC, Wh, Wl);
  trans_k<<<dim3(128, 32, 4), 256, 0, stream>>>(up_w, UpT, 1024, 4096);   // [e][d][f]->[e][f][d]
  trans_k<<<dim3(32, 128, 4), 256, 0, stream>>>(down_w, DnT, 4096, 1024); // [e][f][d]->[e][d][f]

  gemm_k<0><<<dim3(9, 64), 256, 0, stream>>>(Xh, Xl, Wh, Wl, Pf, nullptr,
      bd, bB, bC, nullptr, nullptr, nullptr, nullptr, nullptr, nullptr);

  scan_p<1><<<4096, 256, 0, stream>>>(Pf, x, A_log, D_param, ApB, HeB, nullptr, nullptr, nullptr);
  scan_c   <<<256, 256, 0, stream>>>(ApB, HeB, HiB);
  scan_p<3><<<4096, 256, 0, stream>>>(Pf, x, A_log, D_param, nullptr, nullptr, HiB, SSM, SBF);

  route_k<<<2048, 256, 0, stream>>>(SSM, Wr, br, T1w, T1i, misc);
  build_k<<<1, 1, 0, stream>>>(misc, perm);
  scatter_k<<<32, 256, 0, stream>>>(T1i, misc, perm);

  gemm_k<1><<<dim3(32, MAXTILES), 256, 0, stream>>>(SBF, nullptr, UpT, nullptr,
      nullptr, Hid, up_b, nullptr, nullptr, perm, nullptr, misc + 16, misc + 96, misc + 176, misc + 12);
  gemm_k<2><<<dim3(8, MAXTILES), 256, 0, stream>>>(Hid, nullptr, DnT, nullptr,
      out, nullptr, down_b, nullptr, nullptr, perm, T1w, misc + 16, misc + 96, misc + 176, misc + 12);

  ln_k<<<8192, 256, 0, stream>>>(out, SSM, ln_w, ln_b);
}